// Round 1
// baseline (559.893 us; speedup 1.0000x reference)
//
#include <hip/hip_runtime.h>

typedef __bf16 bf16_t;
typedef __bf16 bf16x8 __attribute__((ext_vector_type(8)));
typedef __bf16 bf16x4 __attribute__((ext_vector_type(4)));
typedef float  f32x4  __attribute__((ext_vector_type(4)));

#define MFMA16(a,b,c) __builtin_amdgcn_mfma_f32_16x16x32_bf16((a),(b),(c),0,0,0)

// ---------- LDS helpers with XOR swizzle (byte ^= (row&7)<<4) ----------
__device__ __forceinline__ bf16x8 lds_read8(const bf16_t* base, int row, int k, int rowB) {
    int byte = row * rowB + (k << 1);
    byte ^= ((row & 7) << 4);
    return *(const bf16x8*)((const char*)base + byte);
}
__device__ __forceinline__ void lds_write1(bf16_t* base, int row, int col, int rowB, float v) {
    int byte = row * rowB + (col << 1);
    byte ^= ((row & 7) << 4);
    *(bf16_t*)((char*)base + byte) = (bf16_t)v;
}
__device__ __forceinline__ float lds_read1(const bf16_t* base, int row, int col, int rowB) {
    int byte = row * rowB + (col << 1);
    byte ^= ((row & 7) << 4);
    return (float)*(const bf16_t*)((const char*)base + byte);
}
__device__ __forceinline__ void lds_write16B(bf16_t* base, int row, int colbyte, int rowB, bf16x8 v) {
    int byte = row * rowB + colbyte;
    byte ^= ((row & 7) << 4);
    *(bf16x8*)((char*)base + byte) = v;
}
__device__ __forceinline__ bf16x8 lds_read16B(const bf16_t* base, int row, int colbyte, int rowB) {
    int byte = row * rowB + colbyte;
    byte ^= ((row & 7) << 4);
    return *(const bf16x8*)((const char*)base + byte);
}

// ---------- generic 64-row x (8 waves x 64-col) layer ----------
// Ain: LDS tile [64][K] bf16 swizzled (rowB_in bytes per row)
// Wb : global bf16 (N=512 rows, K cols) row-major
// out: either LDS [64][512] bf16 swizzled (rowB 1024) or global fp32 rows of 512
template<int K, bool RELU, bool TO_LDS>
__device__ __forceinline__ void gemm_layer(const bf16_t* Ain, int rowB_in,
        const bf16_t* __restrict__ Wb, const float* __restrict__ bias,
        bf16_t* Aout, float* __restrict__ gout, long out_row0,
        int wave, int lane)
{
    const int l15 = lane & 15, lhi = lane >> 4;
    const int n0 = wave * 64;
    f32x4 acc[4][4] = {};
    for (int k0 = 0; k0 < K; k0 += 32) {
        const int k = k0 + lhi * 8;
        bf16x8 a[4], b[4];
#pragma unroll
        for (int rf = 0; rf < 4; ++rf)
            a[rf] = lds_read8(Ain, rf * 16 + l15, k, rowB_in);
#pragma unroll
        for (int cf = 0; cf < 4; ++cf)
            b[cf] = *(const bf16x8*)(Wb + (n0 + cf * 16 + l15) * K + k);
#pragma unroll
        for (int rf = 0; rf < 4; ++rf)
#pragma unroll
            for (int cf = 0; cf < 4; ++cf)
                acc[rf][cf] = MFMA16(a[rf], b[cf], acc[rf][cf]);
    }
#pragma unroll
    for (int cf = 0; cf < 4; ++cf) {
        const int col = n0 + cf * 16 + l15;
        const float bs = bias[col];
#pragma unroll
        for (int rf = 0; rf < 4; ++rf)
#pragma unroll
            for (int r = 0; r < 4; ++r) {
                float v = acc[rf][cf][r] + bs;
                if (RELU) v = fmaxf(v, 0.0f);
                const int row = rf * 16 + lhi * 4 + r;
                if constexpr (TO_LDS) {
                    lds_write1(Aout, row, col, 1024, v);
                } else {
                    gout[(out_row0 + row) * 512 + col] = v;
                }
            }
    }
}

// ---------- kernel 1: cast all weights to bf16 into ws ----------
__global__ __launch_bounds__(256) void cast_kernel(
    const float* __restrict__ W1, const float* __restrict__ W2,
    const float* __restrict__ muW, const float* __restrict__ lvW,
    const float* __restrict__ Wqkv, const float* __restrict__ Wo,
    const float* __restrict__ Wc, const float* __restrict__ Wd1,
    const float* __restrict__ Wd2, const float* __restrict__ Wd3,
    bf16_t* __restrict__ dst)
{
    int i = blockIdx.x * 256 + threadIdx.x;   // grid exactly covers 1376256
    const float* src; int off;
    if      (i <  262144) { src = W1;   off = 0; }
    else if (i <  524288) { src = W2;   off = 262144; }
    else if (i <  655360) { src = muW;  off = 524288; }
    else if (i <  786432) { src = lvW;  off = 655360; }
    else if (i <  798720) { src = Wqkv; off = 786432; }
    else if (i <  802816) { src = Wo;   off = 798720; }
    else if (i <  819200) { src = Wc;   off = 802816; }
    else if (i <  851968) { src = Wd1;  off = 819200; }
    else if (i < 1114112) { src = Wd2;  off = 851968; }
    else                  { src = Wd3;  off = 1114112; }
    dst[i] = (bf16_t)src[i - off];
}

// ---------- kernel 2: encoder + heads + reparameterize ----------
__global__ __launch_bounds__(512) void enc_kernel(
    const float* __restrict__ x, const float* __restrict__ eps,
    const bf16_t* __restrict__ W1b, const float* __restrict__ b1,
    const bf16_t* __restrict__ W2b, const float* __restrict__ b2,
    const bf16_t* __restrict__ Hb,  const float* __restrict__ mub,
    const float* __restrict__ lvb,  bf16_t* __restrict__ zout)
{
    __shared__ bf16_t bufA[64 * 512];
    __shared__ bf16_t bufB[64 * 512];
    const int t = threadIdx.x;
    const size_t r0 = (size_t)blockIdx.x * 64;

    // stage x tile (fp32 -> bf16, swizzled LDS)
    for (int it = 0; it < 16; ++it) {
        int flat = it * 512 + t;
        int row = flat >> 7, c4 = flat & 127;
        float4 v = ((const float4*)(x + (r0 + row) * 512))[c4];
        bf16x4 h = { (bf16_t)v.x, (bf16_t)v.y, (bf16_t)v.z, (bf16_t)v.w };
        int byte = (row << 10) + (c4 << 3);
        byte ^= ((row & 7) << 4);
        *(bf16x4*)((char*)bufA + byte) = h;
    }
    __syncthreads();
    const int wave = t >> 6, lane = t & 63;

    gemm_layer<512, true,  true>(bufA, 1024, W1b, b1, bufB, nullptr, 0, wave, lane);
    __syncthreads();
    gemm_layer<512, true,  true>(bufB, 1024, W2b, b2, bufA, nullptr, 0, wave, lane);
    __syncthreads();
    const float* hb = (wave < 4) ? mub : (lvb - 256);   // cols 0-255 mu, 256-511 lv
    gemm_layer<512, false, true>(bufA, 1024, Hb, hb, bufB, nullptr, 0, wave, lane);
    __syncthreads();

    // z = mu + eps * T^1.5 * exp(0.5*lv_raw)   (log-T folded)
    const int c = t & 255;
    const int a = c >> 6;
    const float tp = (a == 0) ? 1.8371173070873836f
                   : (a == 1) ? 0.35355339059327373f
                   : (a == 2) ? 1.0f
                              : 0.7155417527999327f;
    for (int it = 0; it < 32; ++it) {
        int row = it * 2 + (t >> 8);
        float mu = lds_read1(bufB, row, c, 1024);
        float lv = lds_read1(bufB, row, c + 256, 1024);
        float ep = eps[(r0 + row) * 256 + c];
        float zz = fmaf(ep * tp, expf(0.5f * lv), mu);
        zout[(r0 + row) * 256 + c] = (bf16_t)zz;
    }
}

// ---------- kernel 3: attention over 4 agents + consensus ----------
__global__ __launch_bounds__(512) void attn_kernel(
    const bf16_t* __restrict__ z,
    const bf16_t* __restrict__ Wqkvb, const float* __restrict__ bqkv,
    const bf16_t* __restrict__ Wob,   const float* __restrict__ bo,
    const bf16_t* __restrict__ Wcb,   const float* __restrict__ bc,
    bf16_t* __restrict__ zcb)
{
    __shared__ bf16_t zt[256 * 64];    // z tile, later ctx tile   (rowB 128)
    __shared__ bf16_t qt[256 * 192];   // qkv tile, later z_att    (rowB 384/128)
    const int t = threadIdx.x;
    const size_t s0 = (size_t)blockIdx.x * 64;

    // stage z tile: 256 agent-rows x 64
    for (int it = 0; it < 4; ++it) {
        int ch = it * 512 + t;
        int r = ch >> 3, cc = ch & 7;
        bf16x8 v = *(const bf16x8*)(z + s0 * 256 + r * 64 + cc * 8);
        lds_write16B(zt, r, cc * 16, 128, v);
    }
    __syncthreads();
    const int wave = t >> 6, lane = t & 63, l15 = lane & 15, lhi = lane >> 4;
    const int rbase = wave * 32;

    // qkv: (256 x 192) = zt (256x64) @ Wqkv^T; chunk cols by 48
    for (int cc = 0; cc < 4; ++cc) {
        f32x4 acc[2][3] = {};
#pragma unroll
        for (int ks = 0; ks < 2; ++ks) {
            int k = ks * 32 + lhi * 8;
            bf16x8 a0 = lds_read8(zt, rbase + l15, k, 128);
            bf16x8 a1 = lds_read8(zt, rbase + 16 + l15, k, 128);
#pragma unroll
            for (int cf = 0; cf < 3; ++cf) {
                bf16x8 b = *(const bf16x8*)(Wqkvb + (cc * 48 + cf * 16 + l15) * 64 + k);
                acc[0][cf] = MFMA16(a0, b, acc[0][cf]);
                acc[1][cf] = MFMA16(a1, b, acc[1][cf]);
            }
        }
#pragma unroll
        for (int cf = 0; cf < 3; ++cf) {
            int col = cc * 48 + cf * 16 + l15;
            float bs = bqkv[col];
#pragma unroll
            for (int rf = 0; rf < 2; ++rf)
#pragma unroll
                for (int r = 0; r < 4; ++r)
                    lds_write1(qt, rbase + rf * 16 + lhi * 4 + r, col, 384, acc[rf][cf][r] + bs);
        }
    }
    __syncthreads();

    // per-thread attention: thread = (sample, head), 256 active
    if (t < 256) {
        const int sl = t >> 2, head = t & 3;
        bf16x8 qv[4][2], kv[4][2], vv[4][2];
#pragma unroll
        for (int a2 = 0; a2 < 4; ++a2) {
            int r = sl * 4 + a2;
#pragma unroll
            for (int i = 0; i < 2; ++i) {
                qv[a2][i] = lds_read16B(qt, r, head * 32 + 16 * i, 384);
                kv[a2][i] = lds_read16B(qt, r, 128 + head * 32 + 16 * i, 384);
                vv[a2][i] = lds_read16B(qt, r, 256 + head * 32 + 16 * i, 384);
            }
        }
        float sc[4][4];
#pragma unroll
        for (int qa = 0; qa < 4; ++qa)
#pragma unroll
            for (int ka = 0; ka < 4; ++ka) {
                float s = 0.f;
#pragma unroll
                for (int i = 0; i < 2; ++i)
#pragma unroll
                    for (int j = 0; j < 8; ++j)
                        s += (float)qv[qa][i][j] * (float)kv[ka][i][j];
                sc[qa][ka] = s * 0.25f;
            }
#pragma unroll
        for (int qa = 0; qa < 4; ++qa) {
            float m = fmaxf(fmaxf(sc[qa][0], sc[qa][1]), fmaxf(sc[qa][2], sc[qa][3]));
            float e[4], sum = 0.f;
#pragma unroll
            for (int ka = 0; ka < 4; ++ka) { e[ka] = expf(sc[qa][ka] - m); sum += e[ka]; }
            float inv = 1.f / sum;
#pragma unroll
            for (int i = 0; i < 2; ++i) {
                bf16x8 cv;
#pragma unroll
                for (int j = 0; j < 8; ++j) {
                    float cval = 0.f;
#pragma unroll
                    for (int ka = 0; ka < 4; ++ka) cval += e[ka] * inv * (float)vv[ka][i][j];
                    cv[j] = (bf16_t)cval;
                }
                lds_write16B(zt, sl * 4 + qa, head * 32 + 16 * i, 128, cv);  // ctx into zt
            }
        }
    }
    __syncthreads();

    // z_att = ctx @ Wo^T + bo : (256x64), store into qt as [256][64] rowB 128
    {
        f32x4 acc[2][4] = {};
#pragma unroll
        for (int ks = 0; ks < 2; ++ks) {
            int k = ks * 32 + lhi * 8;
            bf16x8 a0 = lds_read8(zt, rbase + l15, k, 128);
            bf16x8 a1 = lds_read8(zt, rbase + 16 + l15, k, 128);
#pragma unroll
            for (int cf = 0; cf < 4; ++cf) {
                bf16x8 b = *(const bf16x8*)(Wob + (cf * 16 + l15) * 64 + k);
                acc[0][cf] = MFMA16(a0, b, acc[0][cf]);
                acc[1][cf] = MFMA16(a1, b, acc[1][cf]);
            }
        }
        __syncthreads();   // ensure all ctx reads done before overwriting qt
#pragma unroll
        for (int cf = 0; cf < 4; ++cf) {
            int col = cf * 16 + l15;
            float bs = bo[col];
#pragma unroll
            for (int rf = 0; rf < 2; ++rf)
#pragma unroll
                for (int r = 0; r < 4; ++r)
                    lds_write1(qt, rbase + rf * 16 + lhi * 4 + r, col, 128, acc[rf][cf][r] + bs);
        }
    }
    __syncthreads();

    // z_consensus = z_att.reshape(64,256) @ Wc^T + bc : (64x64)
    {
        f32x4 acc2[2] = {};
        const int rfw = wave >> 1, cbase = (wave & 1) * 2;
        const int srow = rfw * 16 + l15;
#pragma unroll
        for (int ks = 0; ks < 8; ++ks) {
            int k = ks * 32 + lhi * 8;
            int byte = (srow << 9) + (k << 1);
            byte ^= ((((srow << 2) + (k >> 6)) & 7) << 4);   // composite swizzle: row = srow*4+(k>>6)
            bf16x8 a = *(const bf16x8*)((const char*)qt + byte);
#pragma unroll
            for (int i = 0; i < 2; ++i) {
                bf16x8 b = *(const bf16x8*)(Wcb + ((cbase + i) * 16 + l15) * 256 + k);
                acc2[i] = MFMA16(a, b, acc2[i]);
            }
        }
#pragma unroll
        for (int i = 0; i < 2; ++i) {
            int col = (cbase + i) * 16 + l15;
            float bs = bc[col];
#pragma unroll
            for (int r = 0; r < 4; ++r) {
                int s = (int)(s0) + rfw * 16 + lhi * 4 + r;
                zcb[(size_t)s * 64 + col] = (bf16_t)(acc2[i][r] + bs);
            }
        }
    }
}

// ---------- kernel 4: fused 3-layer decoder over B*5 rows ----------
__global__ __launch_bounds__(512) void dec_kernel(
    const bf16_t* __restrict__ z, const bf16_t* __restrict__ zc,
    const bf16_t* __restrict__ Wd1b, const float* __restrict__ bd1,
    const bf16_t* __restrict__ Wd2b, const float* __restrict__ bd2,
    const bf16_t* __restrict__ Wd3b, const float* __restrict__ bd3,
    float* __restrict__ out)
{
    __shared__ bf16_t zz[64 * 64];
    __shared__ bf16_t buf1[64 * 512];
    __shared__ bf16_t buf2[64 * 512];
    const int t = threadIdx.x;
    const long r0 = (long)blockIdx.x * 64;

    {   // gather latent rows: row = s*5 + j; j==0 -> consensus, else agent j-1
        int row = t >> 3, ch = t & 7;
        long rg = r0 + row;
        int s = (int)(rg / 5);
        int j = (int)(rg - (long)s * 5);
        const bf16_t* src = (j == 0) ? (zc + (size_t)s * 64)
                                     : (z + (size_t)s * 256 + (j - 1) * 64);
        bf16x8 v = *(const bf16x8*)(src + ch * 8);
        lds_write16B(zz, row, ch * 16, 128, v);
    }
    __syncthreads();
    const int wave = t >> 6, lane = t & 63;

    gemm_layer<64,  true,  true >(zz,   128,  Wd1b, bd1, buf1, nullptr, 0,  wave, lane);
    __syncthreads();
    gemm_layer<512, true,  true >(buf1, 1024, Wd2b, bd2, buf2, nullptr, 0,  wave, lane);
    __syncthreads();
    gemm_layer<512, false, false>(buf2, 1024, Wd3b, bd3, nullptr, out, r0, wave, lane);
}

// ---------- launcher ----------
extern "C" void kernel_launch(void* const* d_in, const int* in_sizes, int n_in,
                              void* d_out, int out_size, void* d_ws, size_t ws_size,
                              hipStream_t stream) {
    const float* x    = (const float*)d_in[0];
    const float* eps  = (const float*)d_in[1];
    const float* W1   = (const float*)d_in[2];
    const float* b1   = (const float*)d_in[3];
    const float* W2   = (const float*)d_in[4];
    const float* b2   = (const float*)d_in[5];
    const float* muW  = (const float*)d_in[6];
    const float* mub  = (const float*)d_in[7];
    const float* lvW  = (const float*)d_in[8];
    const float* lvb  = (const float*)d_in[9];
    const float* Wqkv = (const float*)d_in[10];
    const float* bqkv = (const float*)d_in[11];
    const float* Wo   = (const float*)d_in[12];
    const float* bo   = (const float*)d_in[13];
    const float* Wc   = (const float*)d_in[14];
    const float* bc   = (const float*)d_in[15];
    const float* Wd1  = (const float*)d_in[16];
    const float* bd1  = (const float*)d_in[17];
    const float* Wd2  = (const float*)d_in[18];
    const float* bd2  = (const float*)d_in[19];
    const float* Wd3  = (const float*)d_in[20];
    const float* bd3  = (const float*)d_in[21];
    float* out = (float*)d_out;

    bf16_t* wsb  = (bf16_t*)d_ws;
    bf16_t* W1b  = wsb + 0;
    bf16_t* W2b  = wsb + 262144;
    bf16_t* Hb   = wsb + 524288;    // [muW(256x512) ; lvW(256x512)]
    bf16_t* Wqkvb= wsb + 786432;
    bf16_t* Wob  = wsb + 798720;
    bf16_t* Wcb  = wsb + 802816;
    bf16_t* Wd1b = wsb + 819200;
    bf16_t* Wd2b = wsb + 851968;
    bf16_t* Wd3b = wsb + 1114112;
    bf16_t* zbuf = wsb + 1376256;   // (B,256) bf16
    bf16_t* zcb  = wsb + 9764864;   // (B,64)  bf16

    cast_kernel<<<dim3(5376), dim3(256), 0, stream>>>(
        W1, W2, muW, lvW, Wqkv, Wo, Wc, Wd1, Wd2, Wd3, wsb);
    enc_kernel<<<dim3(512), dim3(512), 0, stream>>>(
        x, eps, W1b, b1, W2b, b2, Hb, mub, lvb, zbuf);
    attn_kernel<<<dim3(512), dim3(512), 0, stream>>>(
        zbuf, Wqkvb, bqkv, Wob, bo, Wcb, bc, zcb);
    dec_kernel<<<dim3(2560), dim3(512), 0, stream>>>(
        zbuf, zcb, Wd1b, bd1, Wd2b, bd2, Wd3b, bd3, out);
}